// Round 2
// baseline (156.612 us; speedup 1.0000x reference)
//
#include <hip/hip_runtime.h>
#include <stdint.h>

typedef unsigned int u32;
typedef unsigned long long u64;

#define BATCH 16
#define NBOX  48384
#define KC    512
#define MAXDET 100
#define CONF_T 0.25f
#define HCUT   0.75f     // high cut: top-512 boundary ~0.857 (product of uniforms)
#define IOU_T  0.45f
#define DET_FLOATS (BATCH*MAXDET*7)            // 11200
#define MASK_OFF   DET_FLOATS                  // 11200
#define FEAT_OFF   (DET_FLOATS + BATCH*MAXDET) // 12800
#define FEAT_N     (BATCH*256*48*48)           // 9437184
#define FEAT4_N    (FEAT_N/4)                  // 2359296

#define CAPH  4096       // per-batch staged-list cap (mean 1656, sd ~40)
#define HBUF  160        // per-block high buffer (mean 26, sd ~5 -> 26 sigma)
#define NBINS 64         // score-histogram bins over [0.75, 1.0)
#define NBLK1 64         // K1 score blocks per batch
#define BOXPB 756        // NBOX / NBLK1
#define K1COPYB 512      // feature-copy blocks fused into k1's grid

__device__ __forceinline__ u64 xorred_u64(u64 v, int m){
    u32 lo = __shfl_xor((u32)(v & 0xFFFFFFFFull), m, 64);
    u32 hi = __shfl_xor((u32)(v >> 32), m, 64);
    return ((u64)hi << 32) | lo;
}
__device__ __forceinline__ u64 shflxor_u64(u64 v, int j){
    u32 lo = __shfl_xor((u32)(v & 0xFFFFFFFFull), j, 64);
    u32 hi = __shfl_xor((u32)(v >> 32), j, 64);
    return ((u64)hi << 32) | lo;
}
__device__ __forceinline__ int score_bin(float sc){
    int bin = (int)((sc - 0.75f) * 256.0f);     // monotone float->bin (identical in k1/k2)
    return bin > 63 ? 63 : bin;
}

// ---- K1: copy blocks (feature passthrough) + scoring blocks (direct float2 reads) ----
//      copy blocks first in grid -> HBM-saturating copy overlaps scoring.
//      Score blocks read ONLY (obj,conf) 8B of each 24B row: 64 lanes cover 1536
//      contiguous bytes -> fully coalesced; no LDS staging needed (boxes are
//      re-read later for just the 512 winners).
__global__ __launch_bounds__(512) void k1_score(const float* __restrict__ pred,
        u64* __restrict__ hkey, u32* __restrict__ blkcnt, u32* __restrict__ ghist,
        float* __restrict__ blkmax, const float4* __restrict__ feat4,
        float* __restrict__ out, int copyB)
{
    __shared__ u64 s_hb[HBUF];
    __shared__ u32 s_hist[NBINS];
    __shared__ u32 s_hc;
    __shared__ float s_wm[8];

    const int tid = threadIdx.x;

    if ((int)blockIdx.x < copyB){                 // feature-copy role
        const int nthr = copyB * 512;
        float4* dst = reinterpret_cast<float4*>(out + FEAT_OFF);
        for (int i = (int)blockIdx.x*512 + tid; i < FEAT4_N; i += nthr)
            dst[i] = feat4[i];
        return;
    }

    const int sid = (int)blockIdx.x - copyB;      // score-block id in [0, 1024)
    const int b = sid >> 6, blk = sid & 63;
    if (tid == 0) s_hc = 0u;
    if (tid < NBINS) s_hist[tid] = 0u;
    __syncthreads();

    const float* pb = pred + ((size_t)b*NBOX + (size_t)blk*BOXPB)*6;
    float m = 0.f;
    for (int i = tid; i < BOXPB; i += 512){
        const float2 oc = *(const float2*)(pb + (size_t)i*6 + 4);  // 8B-aligned
        const float sc = oc.x * oc.y;                    // obj * class_conf
        m = fmaxf(m, sc);
        if (sc >= HCUT){
            const u32 slot = atomicAdd(&s_hc, 1u);       // LDS atomic only (~26/block)
            const u32 idx = (u32)(blk*BOXPB + i);
            if (slot < (u32)HBUF)
                s_hb[slot] = ((u64)__float_as_uint(sc) << 32) | (u64)(0xFFFFFFFFu - idx);
            atomicAdd(&s_hist[score_bin(sc)], 1u);
        }
    }
    #pragma unroll
    for (int off = 32; off >= 1; off >>= 1) m = fmaxf(m, __shfl_xor(m, off, 64));
    if ((tid & 63) == 0) s_wm[tid >> 6] = m;
    __syncthreads();                 // all scoring done; s_hc/s_hist/s_hb final
    if (tid == 0){
        float mm = s_wm[0];
        #pragma unroll
        for (int w = 1; w < 8; w++) mm = fmaxf(mm, s_wm[w]);
        blkmax[sid] = mm;
        blkcnt[sid] = s_hc;          // RAW count; > HBUF forces k2 slow path
    }
    if (tid < NBINS) ghist[(size_t)sid*NBINS + tid] = s_hist[tid];
    const u32 hn = (s_hc < (u32)HBUF ? s_hc : (u32)HBUF);
    for (u32 i = tid; i < hn; i += 512)
        hkey[(size_t)sid*HBUF + i] = s_hb[i];
}

// ---- standalone feature copy (fallback path only; runs LAST to free scratch) ----
__global__ void copy_kernel(const float4* __restrict__ src, float4* __restrict__ dst){
    int stride = gridDim.x * blockDim.x;
    for (int i = blockIdx.x*blockDim.x + threadIdx.x; i < FEAT4_N; i += stride)
        dst[i] = src[i];
}

// ---- K2: per-batch select + sort + gather + IoU + NMS + output, one block/batch ----
//      16 blocks x 1024. All intermediates live in LDS (no cand/mask global
//      round-trips, no extra launches). The 32KB staged-list buffer is
//      time-shared with the 32KB IoU column-mask array.
__global__ __launch_bounds__(1024) void k2_post(
        const float* __restrict__ pred, const u64* __restrict__ hkey,
        const u32* __restrict__ blkcnt, const u32* __restrict__ ghist,
        const float* __restrict__ blkmax, float* __restrict__ out)
{
    __shared__ u64 s_big[4096];      // 32 KB: staged high list, later IoU col masks
    __shared__ u64 s_key[KC];        // 4 KB (low 64 aliased as slow-pass-A scratch)
    __shared__ float4 s_box[KC];     // 8 KB
    __shared__ float s_area[KC];
    __shared__ float s_obj[KC];
    __shared__ float s_conf[KC];
    __shared__ u32 s_scr[1024];      // 4 KB: hist partials (fast) / hist4 (slow)
    __shared__ u64 s_tie[256];       // 2 KB: pivot-bin tie keys (fast)
    __shared__ u32 s_eqidx[256];     // 1 KB: exact-pivot tie indices (slow)
    __shared__ u32 s_pfx[64], s_cnt[64];
    __shared__ u64 s_masks[8];
    __shared__ u32 s_wpcnt[8], s_wpfx[8];
    __shared__ int s_outidx[MAXDET];
    __shared__ float s_thresh;
    __shared__ u32 s_Mh, s_maxc, s_pivbin, s_need, s_fastok;
    __shared__ u32 s_prefix, s_k, s_cntgt, s_cnteq;
    __shared__ int s_vM, s_outcnt;

    const int tid = threadIdx.x;
    const int b = blockIdx.x;
    u64* s_list = s_big;             // staged high list (dead before IoU writes)
    const float* predb = pred + (size_t)b*NBOX*6;

    // 1. wave0: batch max -> threshold; wave1: counts, prefix, total, max
    {
        if (tid < 64){
            float vv = blkmax[b*NBLK1 + tid];
            #pragma unroll
            for (int off = 32; off >= 1; off >>= 1) vv = fmaxf(vv, __shfl_xor(vv, off, 64));
            if (tid == 0){
                float t = CONF_T; int g = 0;
                while (vv < t && g < 256){ t = fmaxf(t - 0.1f, t * 0.1f); g++; }
                s_thresh = t;
                s_cntgt = 0u; s_cnteq = 0u; s_fastok = 0u;
            }
        } else if (tid < 128){
            const int l = tid - 64;
            u32 c = blkcnt[b*NBLK1 + l];
            s_cnt[l] = c;
            u32 p = c;
            #pragma unroll
            for (int off = 1; off < 64; off <<= 1){
                u32 o = __shfl_up(p, off, 64);
                if (l >= off) p += o;
            }
            s_pfx[l] = p - c;                     // exclusive prefix
            u32 mc = c;
            #pragma unroll
            for (int off = 32; off >= 1; off >>= 1) mc = (u32)max(mc, __shfl_xor(mc, off, 64));
            if (l == 63) s_Mh = p;                // inclusive total at last lane
            if (l == 0)  s_maxc = mc;
        }
    }
    __syncthreads();
    const u32 Mh = s_Mh;
    const bool fastm = (Mh >= (u32)KC) && (Mh <= (u32)CAPH) && (s_maxc <= (u32)HBUF);

    // 2. fast: stage fixed-slot segments into contiguous LDS + combine histograms
    if (fastm){
        const int wv = tid >> 6, ln = tid & 63;
        #pragma unroll
        for (int q = 0; q < 4; q++){
            const int s = wv + q*16;
            const u32 n = s_cnt[s], base = s_pfx[s];
            const u64* src = hkey + (size_t)(b*NBLK1 + s)*HBUF;
            for (u32 i = ln; i < n; i += 64) s_list[base + i] = src[i];
        }
        const int j = tid & 63, g = tid >> 6;
        const u32* gh = ghist + (size_t)b*NBLK1*NBINS;
        s_scr[g*64 + j] = gh[(g     )*64 + j] + gh[(g + 16)*64 + j]
                        + gh[(g + 32)*64 + j] + gh[(g + 48)*64 + j];
    }
    __syncthreads();
    if (fastm && tid < 64){                      // wave 0: pivot-bin pick
        u32 h = 0;
        #pragma unroll
        for (int g = 0; g < 16; g++) h += s_scr[g*64 + tid];
        u32 c = h;                               // inclusive suffix over bins (high=large)
        #pragma unroll
        for (int off = 1; off < 64; off <<= 1){
            u32 o = __shfl_down(c, off, 64);
            c += (tid + off < 64) ? o : 0u;
        }
        const u32 above = c - h;                 // count in bins > tid
        if (above < (u32)KC && above + h >= (u32)KC){   // unique crossing bin
            s_pivbin = (u32)tid;
            s_need = (u32)KC - above;
            s_fastok = (h <= 256u) ? 1u : 0u;    // tie buffer capacity gate
        }
    }
    __syncthreads();
    const bool fsel = fastm && (s_fastok != 0u);

    if (fsel){
        // 3a. partition of staged list, wave-aggregated LDS atomics (2 per wave
        //     per round instead of ~100 same-address atomics). Slot order within
        //     a wave differs from serial appends but keys are fully re-sorted and
        //     ties ranked by value -> identical final result.
        const u32 pb = s_pivbin;
        const u32 lane = (u32)(tid & 63);
        const u64 below = (1ull << lane) - 1ull;
        for (u32 i0 = 0; i0 < Mh; i0 += 1024){
            const u32 i = i0 + (u32)tid;
            const bool inr = (i < Mh);
            const u64 key = inr ? s_list[i] : 0ull;
            u32 j2 = 0u;
            if (inr){
                const float sc = __uint_as_float((u32)(key >> 32));
                j2 = (u32)score_bin(sc);
            }
            const bool isgt = inr && (j2 > pb);
            const bool iseq = inr && (j2 == pb);
            const u64 mg = __ballot(isgt);
            const u64 me = __ballot(iseq);
            u32 bg = 0u, be = 0u;
            if (lane == 0u){
                bg = atomicAdd(&s_cntgt, (u32)__popcll(mg));
                be = atomicAdd(&s_cnteq, (u32)__popcll(me));
            }
            bg = (u32)__shfl((int)bg, 0, 64);
            be = (u32)__shfl((int)be, 0, 64);
            if (isgt){
                const u32 sl = bg + (u32)__popcll(mg & below);
                if (sl < (u32)KC) s_key[sl] = key;
            } else if (iseq){
                const u32 e = be + (u32)__popcll(me & below);
                if (e < 256u) s_tie[e] = key;
            }
        }
        __syncthreads();
        // parallel tie rank: keys unique -> rank by value, slot g0+r. Exact.
        {
            const u32 g0v = (s_cntgt < (u32)KC) ? s_cntgt : (u32)KC;
            u32 ecv = (s_cnteq < 256u) ? s_cnteq : 256u;
            u32 needv = (s_need < ecv) ? s_need : ecv;
            if (tid < (int)ecv){
                const u64 me2 = s_tie[tid];
                u32 r = 0;
                for (u32 u2 = 0; u2 < ecv; ++u2) r += (s_tie[u2] > me2) ? 1u : 0u;
                if (r < needv && g0v + r < (u32)KC) s_key[g0v + r] = me2;
            }
            for (int i = (int)(g0v + needv) + tid; i < KC; i += 1024) s_key[i] = 0ull;
        }
        __syncthreads();
    } else {
        // 3b. slow path (never taken with this data): full radix recomputing from pred
        const float thresh = s_thresh;
        const u32 base8 = __float_as_uint(thresh) >> 24;
        u32 (*s_hist4)[256] = reinterpret_cast<u32(*)[256]>(s_scr);
        {   // pass A: 16-bin packed-register histogram (thresh > max/10 -> <16 bins)
            u64 c0=0, c1=0, c2=0, c3=0;
            for (int i = tid; i < NBOX; i += 1024){
                const float* pp = predb + (size_t)i*6;
                float sc = pp[4] * pp[5];
                if (sc >= thresh){
                    u32 d = (__float_as_uint(sc) >> 24) - base8; if (d > 15u) d = 15u;
                    u64 inc = 1ull << (16*(d & 3u)); u32 q = d >> 2;
                    c0 += (q==0u)?inc:0ull; c1 += (q==1u)?inc:0ull;
                    c2 += (q==2u)?inc:0ull; c3 += (q==3u)?inc:0ull;
                }
            }
            #pragma unroll
            for (int off = 32; off >= 1; off >>= 1){
                c0 += xorred_u64(c0,off); c1 += xorred_u64(c1,off);
                c2 += xorred_u64(c2,off); c3 += xorred_u64(c3,off);
            }
            u64* warr = s_key;                   // scratch: 16 waves x 4 u64
            if ((tid & 63) == 0){
                int w = tid >> 6;
                warr[w*4+0]=c0; warr[w*4+1]=c1; warr[w*4+2]=c2; warr[w*4+3]=c3;
            }
            __syncthreads();
            if (tid < 16){
                u32 tot = 0;
                #pragma unroll
                for (int w = 0; w < 16; w++){
                    u64 vv = warr[w*4 + (tid >> 2)];
                    tot += (u32)((vv >> (16*(tid & 3))) & 0xFFFFull);
                }
                s_hist4[0][tid] = tot;
            }
            __syncthreads();
            if (tid == 0){
                u32 h[16]; u32 tot = 0;
                #pragma unroll
                for (int d = 0; d < 16; d++){ h[d] = s_hist4[0][d]; tot += h[d]; }
                s_vM = (int)tot;
                s_k = KC; s_prefix = 0u;
                if (tot > (u32)KC){
                    u32 k = KC, c = 0; int d = 15;
                    for (; d >= 0; --d){ if (c + h[d] >= k) break; c += h[d]; }
                    if (d < 0) d = 0;
                    s_prefix = (base8 + (u32)d) << 24; s_k = k - c;
                }
            }
            __syncthreads();
        }
        const int vM = s_vM;
        if (vM > KC){
            for (int shift = 16; shift >= 0; shift -= 8){
                ((u32*)s_hist4)[tid] = 0u;
                __syncthreads();
                const u32 prefix = s_prefix;
                const u32 pmask = 0xFFFFFFFFu << (shift + 8);
                const int cpy = tid >> 8;
                for (int i = tid; i < NBOX; i += 1024){
                    const float* pp = predb + (size_t)i*6;
                    float sc = pp[4] * pp[5];
                    if (sc >= thresh){
                        u32 bb = __float_as_uint(sc);
                        if ((bb & pmask) == (prefix & pmask))
                            atomicAdd(&s_hist4[cpy][(bb >> shift) & 0xFFu], 1u);
                    }
                }
                __syncthreads();
                if (tid < 256)
                    s_hist4[0][tid] = s_hist4[0][tid] + s_hist4[1][tid]
                                    + s_hist4[2][tid] + s_hist4[3][tid];
                __syncthreads();
                if (tid < 64){                   // wave-parallel digit pick
                    const int l = tid;
                    u32 h0 = s_hist4[0][4*l+0], h1 = s_hist4[0][4*l+1];
                    u32 h2 = s_hist4[0][4*l+2], h3 = s_hist4[0][4*l+3];
                    u32 mysum = h0+h1+h2+h3;
                    u32 c = mysum;
                    #pragma unroll
                    for (int off = 1; off < 64; off <<= 1){
                        u32 o = __shfl_down(c, off, 64);
                        c += (l + off < 64) ? o : 0u;
                    }
                    u32 a3 = c - mysum;
                    u32 a2 = a3 + h3, a1 = a2 + h2, a0 = a1 + h1;
                    u32 k = s_k;
                    int sel = -1; u32 cab = 0;
                    if (a0 < k && a0 + h0 >= k){ sel = 0; cab = a0; }
                    if (a1 < k && a1 + h1 >= k){ sel = 1; cab = a1; }
                    if (a2 < k && a2 + h2 >= k){ sel = 2; cab = a2; }
                    if (a3 < k && a3 + h3 >= k){ sel = 3; cab = a3; }
                    if (sel >= 0){
                        s_prefix = prefix | ((u32)(4*l + sel) << shift);
                        s_k = k - cab;
                    }
                }
                __syncthreads();
            }
        }
        const u32 pivot = (vM > KC) ? s_prefix : 0u;
        const bool pivot0 = (vM <= KC);
        const int kneed = pivot0 ? 0 : (int)s_k;
        for (int i = tid; i < NBOX; i += 1024){
            const float* pp = predb + (size_t)i*6;
            float sc = pp[4] * pp[5];
            if (sc < thresh) continue;
            u32 bb = __float_as_uint(sc);
            if (bb > pivot){
                u32 sl = atomicAdd(&s_cntgt, 1u);
                if (sl < (u32)KC) s_key[sl] = ((u64)bb << 32) | (u64)(0xFFFFFFFFu - (u32)i);
            } else if (!pivot0 && bb == pivot){
                u32 e = atomicAdd(&s_cnteq, 1u);
                if (e < 256u) s_eqidx[e] = (u32)i;
            }
        }
        __syncthreads();
        if (tid == 0){
            int g = (int)s_cntgt; if (g > KC) g = KC;
            int ec = (int)s_cnteq; if (ec > 256) ec = 256;
            int need = kneed < ec ? kneed : ec;
            for (int t = 0; t < need; t++){      // lowest indices first at exact pivot
                int mi = t;
                for (int u = t+1; u < ec; u++) if (s_eqidx[u] < s_eqidx[mi]) mi = u;
                u32 tmp = s_eqidx[mi]; s_eqidx[mi] = s_eqidx[t]; s_eqidx[t] = tmp;
                if (g < KC) s_key[g++] = ((u64)pivot << 32) | (u64)(0xFFFFFFFFu - tmp);
            }
            while (g < KC) s_key[g++] = 0ull;
        }
        __syncthreads();
    }

    // 4. bitonic sort 512 keys descending — shfl for j<=32, LDS for j in {64,128,256}
    u64 v = (tid < KC) ? s_key[tid] : 0ull;
    {
        #define CAS_W(kk, j) \
            if (tid < KC){ \
                u64 p = shflxor_u64(v, (j)); \
                bool keepMax = (((tid & (kk)) == 0) == ((tid & (j)) == 0)); \
                u64 mx = (v > p) ? v : p, mn = (v > p) ? p : v; \
                v = keepMax ? mx : mn; \
            }
        #define CAS_L(kk, j) \
            __syncthreads(); \
            if (tid < KC) s_key[tid] = v; \
            __syncthreads(); \
            if (tid < KC){ \
                u64 p = s_key[tid ^ (j)]; \
                bool keepMax = (((tid & (kk)) == 0) == ((tid & (j)) == 0)); \
                u64 mx = (v > p) ? v : p, mn = (v > p) ? p : v; \
                v = keepMax ? mx : mn; \
            }
        CAS_W(2,1)
        CAS_W(4,2)  CAS_W(4,1)
        CAS_W(8,4)  CAS_W(8,2)  CAS_W(8,1)
        CAS_W(16,8) CAS_W(16,4) CAS_W(16,2) CAS_W(16,1)
        CAS_W(32,16) CAS_W(32,8) CAS_W(32,4) CAS_W(32,2) CAS_W(32,1)
        CAS_W(64,32) CAS_W(64,16) CAS_W(64,8) CAS_W(64,4) CAS_W(64,2) CAS_W(64,1)
        CAS_L(128,64)
        CAS_W(128,32) CAS_W(128,16) CAS_W(128,8) CAS_W(128,4) CAS_W(128,2) CAS_W(128,1)
        CAS_L(256,128) CAS_L(256,64)
        CAS_W(256,32) CAS_W(256,16) CAS_W(256,8) CAS_W(256,4) CAS_W(256,2) CAS_W(256,1)
        CAS_L(512,256) CAS_L(512,128) CAS_L(512,64)
        CAS_W(512,32) CAS_W(512,16) CAS_W(512,8) CAS_W(512,4) CAS_W(512,2) CAS_W(512,1)
        #undef CAS_W
        #undef CAS_L
    }

    // 5. gather candidate boxes into LDS (op-for-op identical reference box math);
    //    rows are 24B (8B-aligned) -> three float2 loads per winner.
    if (tid < KC){
        u32 bb = (u32)(v >> 32);
        u32 idx = 0xFFFFFFFFu - (u32)(v & 0xFFFFFFFFull);
        int srcrow = (bb != 0u) ? (int)idx : 0;
        const float* p = predb + (size_t)srcrow*6;
        const float2 p01 = *(const float2*)(p);
        const float2 p23 = *(const float2*)(p + 2);
        const float2 p45 = *(const float2*)(p + 4);
        float cx = p01.x, cy = p01.y, w = p23.x, h = p23.y, ob = p45.x, cf = p45.y;
        float x1 = cx - w * 0.5f, y1 = cy - h * 0.5f;
        float x2 = cx + w * 0.5f, y2 = cy + h * 0.5f;
        s_box[tid] = make_float4(x1, y1, x2, y2);
        s_area[tid] = fmaxf(x2 - x1, 0.f) * fmaxf(y2 - y1, 0.f);
        s_obj[tid] = ob; s_conf[tid] = cf;
    }
    __syncthreads();                 // gather done; s_list dead -> s_big reusable

    // 6. IoU column masks in s_big: col[c][j] bit t = (cand c*64+t suppresses cand j)
    {
        const int wave = tid >> 6, lane = tid & 63;
        for (int p = wave; p < 36; p += 16){
            int d = 0; while ((d+1)*(d+2)/2 <= p) d++;
            int c = p - d*(d+1)/2;
            const int j = d*64 + lane;
            const float4 bj = s_box[j];
            const float aj = s_area[j];
            u64 acc = 0ull;
            for (int t = 0; t < 64; t++){
                const float4 bi = s_box[c*64 + t];           // wave-uniform -> broadcast
                const float ai = s_area[c*64 + t];
                float lx = fmaxf(bi.x, bj.x), ly = fmaxf(bi.y, bj.y);
                float rx = fminf(bi.z, bj.z), ry = fminf(bi.w, bj.w);
                float iw = fmaxf(rx - lx, 0.f), ih = fmaxf(ry - ly, 0.f);
                float inter = iw * ih;
                float denom = ai + aj - inter + 1e-9f;
                bool sup = (inter > IOU_T * denom) && (c < d || t < lane);
                acc |= sup ? (1ull << t) : 0ull;
            }
            s_big[(size_t)c*512 + j] = acc;
        }
    }
    __syncthreads();

    // 7. staged greedy NMS (exact order): 8 blocks of 64, ballot within block
    {
        const int wave = tid >> 6, lane = tid & 63;
        bool alive = (tid < KC) && (((u32)(v >> 32)) != 0u);
        for (int c = 0; c < 8; c++){
            if (wave == c){
                #pragma unroll
                for (int e = 0; e < 8; e++)
                    if (e < c) alive = alive && ((s_big[(size_t)e*512 + c*64 + lane] & s_masks[e]) == 0ull);
                const u64 diag = s_big[(size_t)c*512 + c*64 + lane];
                for (int t = 0; t < 64; t++){
                    u64 mnow = __ballot(alive);
                    bool at = (mnow >> t) & 1ull;
                    alive = alive && !(at && ((diag >> t) & 1ull));
                }
                u64 fin = __ballot(alive);
                if (lane == 0) s_masks[c] = fin;
            }
            __syncthreads();
        }
    }

    // 8. parallel rank of kept candidates -> det + mask; rest exact zeros
    if (tid < 8) s_wpcnt[tid] = (u32)__popcll(s_masks[tid]);
    __syncthreads();
    if (tid == 0){
        u32 run = 0;
        #pragma unroll
        for (int w = 0; w < 8; w++){ s_wpfx[w] = run; run += s_wpcnt[w]; }
        s_outcnt = (int)(run < MAXDET ? run : MAXDET);
    }
    __syncthreads();
    if (tid < KC){
        const int w = tid >> 6, l = tid & 63;
        const u64 wd = s_masks[w];
        if ((wd >> l) & 1ull){
            u32 rank = s_wpfx[w] + (u32)__popcll(wd & ((1ull << l) - 1ull));
            if (rank < MAXDET) s_outidx[rank] = tid;
        }
    }
    __syncthreads();
    if (tid < MAXDET){
        const int obase = (b * MAXDET + tid) * 7;
        if (tid < s_outcnt){
            int c = s_outidx[tid];
            float4 bx = s_box[c];
            out[obase+0] = bx.x; out[obase+1] = bx.y;
            out[obase+2] = bx.z; out[obase+3] = bx.w;
            out[obase+4] = s_obj[c]; out[obase+5] = s_conf[c];
            out[obase+6] = 0.f;                     // class_pred == 0 (NUM_CLASSES==1)
            out[MASK_OFF + b*MAXDET + tid] = 1.f;
        } else {
            #pragma unroll
            for (int q = 0; q < 7; q++) out[obase+q] = 0.f;
            out[MASK_OFF + b*MAXDET + tid] = 0.f;
        }
    }
}

extern "C" void kernel_launch(void* const* d_in, const int* in_sizes, int n_in,
                              void* d_out, int out_size, void* d_ws, size_t ws_size,
                              hipStream_t stream) {
    (void)in_sizes; (void)n_in; (void)out_size;
    const float* pred = (const float*)d_in[0];
    const float* feat = (const float*)d_in[1];
    float* out = (float*)d_out;

    const size_t hkeyBytes = (size_t)BATCH * NBLK1 * HBUF * 8;   // 1,310,720
    const size_t cntBytes  = (size_t)BATCH * NBLK1 * 4;          // 4,096
    const size_t histBytes = (size_t)BATCH * NBLK1 * NBINS * 4;  // 262,144
    const size_t maxBytes  = (size_t)BATCH * NBLK1 * 4;          // 4,096
    const size_t needBytes = hkeyBytes + cntBytes + histBytes + maxBytes; // unchanged

    char* base; bool fused;
    if (ws_size >= needBytes){ base = (char*)d_ws; fused = true; }
    else { base = (char*)(out + FEAT_OFF); fused = false; }   // not-yet-written features

    u64* hkeyp  = (u64*)base;
    u32* blkcnt = (u32*)(base + hkeyBytes);
    u32* ghist  = (u32*)(base + hkeyBytes + cntBytes);
    float* blkmax = (float*)(base + hkeyBytes + cntBytes + histBytes);

    if (fused){
        // copy fused into k1 (overlaps scoring); scratch lives in d_ws
        k1_score<<<dim3(K1COPYB + BATCH*NBLK1), dim3(512), 0, stream>>>(
            pred, hkeyp, blkcnt, ghist, blkmax, (const float4*)feat, out, K1COPYB);
        k2_post<<<dim3(BATCH), dim3(1024), 0, stream>>>(
            pred, hkeyp, blkcnt, ghist, blkmax, out);
    } else {
        // scratch lives in the feature output region -> copy must run LAST
        k1_score<<<dim3(BATCH*NBLK1), dim3(512), 0, stream>>>(
            pred, hkeyp, blkcnt, ghist, blkmax, (const float4*)feat, out, 0);
        k2_post<<<dim3(BATCH), dim3(1024), 0, stream>>>(
            pred, hkeyp, blkcnt, ghist, blkmax, out);
        copy_kernel<<<dim3(1024), dim3(256), 0, stream>>>(
            (const float4*)feat, (float4*)(out + FEAT_OFF));
    }
}

// Round 3
// 135.355 us; speedup vs baseline: 1.1570x; 1.1570x over previous
//
#include <hip/hip_runtime.h>
#include <stdint.h>

typedef unsigned int u32;
typedef unsigned long long u64;

#define BATCH 16
#define NBOX  48384
#define KC    512
#define MAXDET 100
#define CONF_T 0.25f
#define HCUT   0.75f     // high cut: top-512 boundary ~0.857 (product of uniforms)
#define IOU_T  0.45f
#define DET_FLOATS (BATCH*MAXDET*7)            // 11200
#define MASK_OFF   DET_FLOATS                  // 11200
#define FEAT_OFF   (DET_FLOATS + BATCH*MAXDET) // 12800
#define FEAT_N     (BATCH*256*48*48)           // 9437184
#define FEAT4_N    (FEAT_N/4)                  // 2359296

#define CAPH  4096       // per-batch staged-list cap (mean 1656, sd ~40)
#define HBUF  160        // per-block high buffer (mean 26, sd ~5 -> 26 sigma)
#define NBINS 64         // score-histogram bins over [0.75, 1.0)
#define NBLK1 64         // K1 score blocks per batch
#define BOXPB 756        // NBOX / NBLK1

// feature-copy slices, one per launch (overlap copy with latency-bound phases)
#define F64   (FEAT4_N/64)       // 36864
#define CSL1  (13*F64)           // k1 slice: [0, CSL1)
#define CSL2  (45*F64)           // k2a slice: [CSL1, CSL2)   (32/64)
#define CSL3  (54*F64)           // k2b slice: [CSL2, CSL3)   (9/64)
                                 // k2c slice: [CSL3, FEAT4_N) (10/64)
#define K1CPB  256
#define K2ACPB 240
#define K2BCPB 192
#define K2CCPB 240

__device__ __forceinline__ u64 xorred_u64(u64 v, int m){
    u32 lo = __shfl_xor((u32)(v & 0xFFFFFFFFull), m, 64);
    u32 hi = __shfl_xor((u32)(v >> 32), m, 64);
    return ((u64)hi << 32) | lo;
}
__device__ __forceinline__ u64 shflxor_u64(u64 v, int j){
    u32 lo = __shfl_xor((u32)(v & 0xFFFFFFFFull), j, 64);
    u32 hi = __shfl_xor((u32)(v >> 32), j, 64);
    return ((u64)hi << 32) | lo;
}
__device__ __forceinline__ u64 shflidx_u64(u64 v, int src){
    u32 lo = (u32)__shfl((int)(u32)(v & 0xFFFFFFFFull), src, 64);
    u32 hi = (u32)__shfl((int)(u32)(v >> 32), src, 64);
    return ((u64)hi << 32) | lo;
}
__device__ __forceinline__ int score_bin(float sc){
    int bin = (int)((sc - 0.75f) * 256.0f);     // monotone float->bin (identical in k1/k2a)
    return bin > 63 ? 63 : bin;
}

// ---- K1: copy blocks (slice 1) + scoring blocks (direct float2 reads) ----
__global__ __launch_bounds__(512) void k1_score(const float* __restrict__ pred,
        u64* __restrict__ hkey, u32* __restrict__ blkcnt, u32* __restrict__ ghist,
        float* __restrict__ blkmax, const float4* __restrict__ feat4,
        float* __restrict__ out, int copyB)
{
    __shared__ u64 s_hb[HBUF];
    __shared__ u32 s_hist[NBINS];
    __shared__ u32 s_hc;
    __shared__ float s_wm[8];

    const int tid = threadIdx.x;

    if ((int)blockIdx.x < copyB){                 // feature-copy role: [0, CSL1)
        const int nthr = copyB * 512;
        float4* dst = reinterpret_cast<float4*>(out + FEAT_OFF);
        for (int i = (int)blockIdx.x*512 + tid; i < CSL1; i += nthr)
            dst[i] = feat4[i];
        return;
    }

    const int sid = (int)blockIdx.x - copyB;      // score-block id in [0, 1024)
    const int b = sid >> 6, blk = sid & 63;
    if (tid == 0) s_hc = 0u;
    if (tid < NBINS) s_hist[tid] = 0u;
    __syncthreads();

    const float* pb = pred + ((size_t)b*NBOX + (size_t)blk*BOXPB)*6;
    float m = 0.f;
    for (int i = tid; i < BOXPB; i += 512){
        const float2 oc = *(const float2*)(pb + (size_t)i*6 + 4);  // 8B-aligned
        const float sc = oc.x * oc.y;                    // obj * class_conf
        m = fmaxf(m, sc);
        if (sc >= HCUT){
            const u32 slot = atomicAdd(&s_hc, 1u);       // LDS atomic only (~26/block)
            const u32 idx = (u32)(blk*BOXPB + i);
            if (slot < (u32)HBUF)
                s_hb[slot] = ((u64)__float_as_uint(sc) << 32) | (u64)(0xFFFFFFFFu - idx);
            atomicAdd(&s_hist[score_bin(sc)], 1u);
        }
    }
    #pragma unroll
    for (int off = 32; off >= 1; off >>= 1) m = fmaxf(m, __shfl_xor(m, off, 64));
    if ((tid & 63) == 0) s_wm[tid >> 6] = m;
    __syncthreads();                 // all scoring done; s_hc/s_hist/s_hb final
    if (tid == 0){
        float mm = s_wm[0];
        #pragma unroll
        for (int w = 1; w < 8; w++) mm = fmaxf(mm, s_wm[w]);
        blkmax[sid] = mm;
        blkcnt[sid] = s_hc;          // RAW count; > HBUF forces k2a slow path
    }
    if (tid < NBINS) ghist[(size_t)sid*NBINS + tid] = s_hist[tid];
    const u32 hn = (s_hc < (u32)HBUF ? s_hc : (u32)HBUF);
    for (u32 i = tid; i < hn; i += 512)
        hkey[(size_t)sid*HBUF + i] = s_hb[i];
}

// ---- standalone feature copy (fallback path only; runs LAST to free scratch) ----
__global__ void copy_kernel(const float4* __restrict__ src, float4* __restrict__ dst){
    int stride = gridDim.x * blockDim.x;
    for (int i = blockIdx.x*blockDim.x + threadIdx.x; i < FEAT4_N; i += stride)
        dst[i] = src[i];
}

// ---- K2a: per-batch select + sort + gather (16 compute blocks + copy slice 2) ----
//      writes 512 candidate records/batch into the ghist window this block consumed:
//      cand[b][i] = { float4 box ; float4 (area, obj, conf, scorebits) }  (32 B)
__global__ __launch_bounds__(1024) void k2a_sel(
        const float* __restrict__ pred, const u64* __restrict__ hkey,
        const u32* __restrict__ blkcnt, u32* ghist /*aliased with cand output*/,
        const float* __restrict__ blkmax,
        const float4* __restrict__ feat4, float* __restrict__ out, int copyB)
{
    __shared__ u64 s_list[CAPH];     // 32 KB staged high list
    __shared__ u64 s_key[KC];        // 4 KB (low 64 aliased as slow-pass-A scratch)
    __shared__ u32 s_scr[1024];      // 4 KB: hist partials (fast) / hist4 (slow)
    __shared__ u64 s_tie[256];       // 2 KB: pivot-bin tie keys (fast)
    __shared__ u32 s_eqidx[256];     // 1 KB: exact-pivot tie indices (slow)
    __shared__ u32 s_pfx[64], s_cnt[64];
    __shared__ float s_thresh;
    __shared__ u32 s_Mh, s_maxc, s_pivbin, s_need, s_fastok;
    __shared__ u32 s_prefix, s_k, s_cntgt, s_cnteq;
    __shared__ int s_vM;

    const int tid = threadIdx.x;

    if ((int)blockIdx.x >= BATCH){                // copy role: [CSL1, CSL2)
        const int nthr = copyB * 1024;
        float4* dst = reinterpret_cast<float4*>(out + FEAT_OFF);
        for (int i = CSL1 + ((int)blockIdx.x - BATCH)*1024 + tid; i < CSL2; i += nthr)
            dst[i] = feat4[i];
        return;
    }

    const int b = blockIdx.x;
    const float* predb = pred + (size_t)b*NBOX*6;

    // 1. wave0: batch max -> threshold; wave1: counts, prefix, total, max
    {
        if (tid < 64){
            float vv = blkmax[b*NBLK1 + tid];
            #pragma unroll
            for (int off = 32; off >= 1; off >>= 1) vv = fmaxf(vv, __shfl_xor(vv, off, 64));
            if (tid == 0){
                float t = CONF_T; int g = 0;
                while (vv < t && g < 256){ t = fmaxf(t - 0.1f, t * 0.1f); g++; }
                s_thresh = t;
                s_cntgt = 0u; s_cnteq = 0u; s_fastok = 0u;
            }
        } else if (tid < 128){
            const int l = tid - 64;
            u32 c = blkcnt[b*NBLK1 + l];
            s_cnt[l] = c;
            u32 p = c;
            #pragma unroll
            for (int off = 1; off < 64; off <<= 1){
                u32 o = __shfl_up(p, off, 64);
                if (l >= off) p += o;
            }
            s_pfx[l] = p - c;                     // exclusive prefix
            u32 mc = c;
            #pragma unroll
            for (int off = 32; off >= 1; off >>= 1) mc = (u32)max(mc, __shfl_xor(mc, off, 64));
            if (l == 63) s_Mh = p;                // inclusive total at last lane
            if (l == 0)  s_maxc = mc;
        }
    }
    __syncthreads();
    const u32 Mh = s_Mh;
    const bool fastm = (Mh >= (u32)KC) && (Mh <= (u32)CAPH) && (s_maxc <= (u32)HBUF);

    // 2. fast: stage fixed-slot segments into contiguous LDS + combine histograms
    if (fastm){
        const int wv = tid >> 6, ln = tid & 63;
        #pragma unroll
        for (int q = 0; q < 4; q++){
            const int s = wv + q*16;
            const u32 n = s_cnt[s], base = s_pfx[s];
            const u64* src = hkey + (size_t)(b*NBLK1 + s)*HBUF;
            for (u32 i = ln; i < n; i += 64) s_list[base + i] = src[i];
        }
        const int j = tid & 63, g = tid >> 6;
        const u32* gh = ghist + (size_t)b*NBLK1*NBINS;
        s_scr[g*64 + j] = gh[(g     )*64 + j] + gh[(g + 16)*64 + j]
                        + gh[(g + 32)*64 + j] + gh[(g + 48)*64 + j];
    }
    __syncthreads();
    if (fastm && tid < 64){                      // wave 0: pivot-bin pick
        u32 h = 0;
        #pragma unroll
        for (int g = 0; g < 16; g++) h += s_scr[g*64 + tid];
        u32 c = h;                               // inclusive suffix over bins (high=large)
        #pragma unroll
        for (int off = 1; off < 64; off <<= 1){
            u32 o = __shfl_down(c, off, 64);
            c += (tid + off < 64) ? o : 0u;
        }
        const u32 above = c - h;                 // count in bins > tid
        if (above < (u32)KC && above + h >= (u32)KC){   // unique crossing bin
            s_pivbin = (u32)tid;
            s_need = (u32)KC - above;
            s_fastok = (h <= 256u) ? 1u : 0u;    // tie buffer capacity gate
        }
    }
    __syncthreads();
    const bool fsel = fastm && (s_fastok != 0u);

    if (fsel){
        // 3a. partition of staged list, wave-aggregated LDS atomics (validated r2)
        const u32 pb = s_pivbin;
        const u32 lane = (u32)(tid & 63);
        const u64 below = (1ull << lane) - 1ull;
        for (u32 i0 = 0; i0 < Mh; i0 += 1024){
            const u32 i = i0 + (u32)tid;
            const bool inr = (i < Mh);
            const u64 key = inr ? s_list[i] : 0ull;
            u32 j2 = 0u;
            if (inr){
                const float sc = __uint_as_float((u32)(key >> 32));
                j2 = (u32)score_bin(sc);
            }
            const bool isgt = inr && (j2 > pb);
            const bool iseq = inr && (j2 == pb);
            const u64 mg = __ballot(isgt);
            const u64 me = __ballot(iseq);
            u32 bg = 0u, be = 0u;
            if (lane == 0u){
                bg = atomicAdd(&s_cntgt, (u32)__popcll(mg));
                be = atomicAdd(&s_cnteq, (u32)__popcll(me));
            }
            bg = (u32)__shfl((int)bg, 0, 64);
            be = (u32)__shfl((int)be, 0, 64);
            if (isgt){
                const u32 sl = bg + (u32)__popcll(mg & below);
                if (sl < (u32)KC) s_key[sl] = key;
            } else if (iseq){
                const u32 e = be + (u32)__popcll(me & below);
                if (e < 256u) s_tie[e] = key;
            }
        }
        __syncthreads();
        // parallel tie rank: keys unique -> rank by value, slot g0+r. Exact.
        {
            const u32 g0v = (s_cntgt < (u32)KC) ? s_cntgt : (u32)KC;
            u32 ecv = (s_cnteq < 256u) ? s_cnteq : 256u;
            u32 needv = (s_need < ecv) ? s_need : ecv;
            if (tid < (int)ecv){
                const u64 me2 = s_tie[tid];
                u32 r = 0;
                for (u32 u2 = 0; u2 < ecv; ++u2) r += (s_tie[u2] > me2) ? 1u : 0u;
                if (r < needv && g0v + r < (u32)KC) s_key[g0v + r] = me2;
            }
            for (int i = (int)(g0v + needv) + tid; i < KC; i += 1024) s_key[i] = 0ull;
        }
        __syncthreads();
    } else {
        // 3b. slow path (never taken with this data): full radix recomputing from pred
        const float thresh = s_thresh;
        const u32 base8 = __float_as_uint(thresh) >> 24;
        u32 (*s_hist4)[256] = reinterpret_cast<u32(*)[256]>(s_scr);
        {   // pass A: 16-bin packed-register histogram (thresh > max/10 -> <16 bins)
            u64 c0=0, c1=0, c2=0, c3=0;
            for (int i = tid; i < NBOX; i += 1024){
                const float* pp = predb + (size_t)i*6;
                float sc = pp[4] * pp[5];
                if (sc >= thresh){
                    u32 d = (__float_as_uint(sc) >> 24) - base8; if (d > 15u) d = 15u;
                    u64 inc = 1ull << (16*(d & 3u)); u32 q = d >> 2;
                    c0 += (q==0u)?inc:0ull; c1 += (q==1u)?inc:0ull;
                    c2 += (q==2u)?inc:0ull; c3 += (q==3u)?inc:0ull;
                }
            }
            #pragma unroll
            for (int off = 32; off >= 1; off >>= 1){
                c0 += xorred_u64(c0,off); c1 += xorred_u64(c1,off);
                c2 += xorred_u64(c2,off); c3 += xorred_u64(c3,off);
            }
            u64* warr = s_key;                   // scratch: 16 waves x 4 u64
            if ((tid & 63) == 0){
                int w = tid >> 6;
                warr[w*4+0]=c0; warr[w*4+1]=c1; warr[w*4+2]=c2; warr[w*4+3]=c3;
            }
            __syncthreads();
            if (tid < 16){
                u32 tot = 0;
                #pragma unroll
                for (int w = 0; w < 16; w++){
                    u64 vv = warr[w*4 + (tid >> 2)];
                    tot += (u32)((vv >> (16*(tid & 3))) & 0xFFFFull);
                }
                s_hist4[0][tid] = tot;
            }
            __syncthreads();
            if (tid == 0){
                u32 h[16]; u32 tot = 0;
                #pragma unroll
                for (int d = 0; d < 16; d++){ h[d] = s_hist4[0][d]; tot += h[d]; }
                s_vM = (int)tot;
                s_k = KC; s_prefix = 0u;
                if (tot > (u32)KC){
                    u32 k = KC, c = 0; int d = 15;
                    for (; d >= 0; --d){ if (c + h[d] >= k) break; c += h[d]; }
                    if (d < 0) d = 0;
                    s_prefix = (base8 + (u32)d) << 24; s_k = k - c;
                }
            }
            __syncthreads();
        }
        const int vM = s_vM;
        if (vM > KC){
            for (int shift = 16; shift >= 0; shift -= 8){
                ((u32*)s_hist4)[tid] = 0u;
                __syncthreads();
                const u32 prefix = s_prefix;
                const u32 pmask = 0xFFFFFFFFu << (shift + 8);
                const int cpy = tid >> 8;
                for (int i = tid; i < NBOX; i += 1024){
                    const float* pp = predb + (size_t)i*6;
                    float sc = pp[4] * pp[5];
                    if (sc >= thresh){
                        u32 bb = __float_as_uint(sc);
                        if ((bb & pmask) == (prefix & pmask))
                            atomicAdd(&s_hist4[cpy][(bb >> shift) & 0xFFu], 1u);
                    }
                }
                __syncthreads();
                if (tid < 256)
                    s_hist4[0][tid] = s_hist4[0][tid] + s_hist4[1][tid]
                                    + s_hist4[2][tid] + s_hist4[3][tid];
                __syncthreads();
                if (tid < 64){                   // wave-parallel digit pick
                    const int l = tid;
                    u32 h0 = s_hist4[0][4*l+0], h1 = s_hist4[0][4*l+1];
                    u32 h2 = s_hist4[0][4*l+2], h3 = s_hist4[0][4*l+3];
                    u32 mysum = h0+h1+h2+h3;
                    u32 c = mysum;
                    #pragma unroll
                    for (int off = 1; off < 64; off <<= 1){
                        u32 o = __shfl_down(c, off, 64);
                        c += (l + off < 64) ? o : 0u;
                    }
                    u32 a3 = c - mysum;
                    u32 a2 = a3 + h3, a1 = a2 + h2, a0 = a1 + h1;
                    u32 k = s_k;
                    int sel = -1; u32 cab = 0;
                    if (a0 < k && a0 + h0 >= k){ sel = 0; cab = a0; }
                    if (a1 < k && a1 + h1 >= k){ sel = 1; cab = a1; }
                    if (a2 < k && a2 + h2 >= k){ sel = 2; cab = a2; }
                    if (a3 < k && a3 + h3 >= k){ sel = 3; cab = a3; }
                    if (sel >= 0){
                        s_prefix = prefix | ((u32)(4*l + sel) << shift);
                        s_k = k - cab;
                    }
                }
                __syncthreads();
            }
        }
        const u32 pivot = (vM > KC) ? s_prefix : 0u;
        const bool pivot0 = (vM <= KC);
        const int kneed = pivot0 ? 0 : (int)s_k;
        for (int i = tid; i < NBOX; i += 1024){
            const float* pp = predb + (size_t)i*6;
            float sc = pp[4] * pp[5];
            if (sc < thresh) continue;
            u32 bb = __float_as_uint(sc);
            if (bb > pivot){
                u32 sl = atomicAdd(&s_cntgt, 1u);
                if (sl < (u32)KC) s_key[sl] = ((u64)bb << 32) | (u64)(0xFFFFFFFFu - (u32)i);
            } else if (!pivot0 && bb == pivot){
                u32 e = atomicAdd(&s_cnteq, 1u);
                if (e < 256u) s_eqidx[e] = (u32)i;
            }
        }
        __syncthreads();
        if (tid == 0){
            int g = (int)s_cntgt; if (g > KC) g = KC;
            int ec = (int)s_cnteq; if (ec > 256) ec = 256;
            int need = kneed < ec ? kneed : ec;
            for (int t = 0; t < need; t++){      // lowest indices first at exact pivot
                int mi = t;
                for (int u = t+1; u < ec; u++) if (s_eqidx[u] < s_eqidx[mi]) mi = u;
                u32 tmp = s_eqidx[mi]; s_eqidx[mi] = s_eqidx[t]; s_eqidx[t] = tmp;
                if (g < KC) s_key[g++] = ((u64)pivot << 32) | (u64)(0xFFFFFFFFu - tmp);
            }
            while (g < KC) s_key[g++] = 0ull;
        }
        __syncthreads();
    }

    // 4. bitonic sort 512 keys descending — shfl for j<=32, LDS for j in {64,128,256}
    u64 v = (tid < KC) ? s_key[tid] : 0ull;
    {
        #define CAS_W(kk, j) \
            if (tid < KC){ \
                u64 p = shflxor_u64(v, (j)); \
                bool keepMax = (((tid & (kk)) == 0) == ((tid & (j)) == 0)); \
                u64 mx = (v > p) ? v : p, mn = (v > p) ? p : v; \
                v = keepMax ? mx : mn; \
            }
        #define CAS_L(kk, j) \
            __syncthreads(); \
            if (tid < KC) s_key[tid] = v; \
            __syncthreads(); \
            if (tid < KC){ \
                u64 p = s_key[tid ^ (j)]; \
                bool keepMax = (((tid & (kk)) == 0) == ((tid & (j)) == 0)); \
                u64 mx = (v > p) ? v : p, mn = (v > p) ? p : v; \
                v = keepMax ? mx : mn; \
            }
        CAS_W(2,1)
        CAS_W(4,2)  CAS_W(4,1)
        CAS_W(8,4)  CAS_W(8,2)  CAS_W(8,1)
        CAS_W(16,8) CAS_W(16,4) CAS_W(16,2) CAS_W(16,1)
        CAS_W(32,16) CAS_W(32,8) CAS_W(32,4) CAS_W(32,2) CAS_W(32,1)
        CAS_W(64,32) CAS_W(64,16) CAS_W(64,8) CAS_W(64,4) CAS_W(64,2) CAS_W(64,1)
        CAS_L(128,64)
        CAS_W(128,32) CAS_W(128,16) CAS_W(128,8) CAS_W(128,4) CAS_W(128,2) CAS_W(128,1)
        CAS_L(256,128) CAS_L(256,64)
        CAS_W(256,32) CAS_W(256,16) CAS_W(256,8) CAS_W(256,4) CAS_W(256,2) CAS_W(256,1)
        CAS_L(512,256) CAS_L(512,128) CAS_L(512,64)
        CAS_W(512,32) CAS_W(512,16) CAS_W(512,8) CAS_W(512,4) CAS_W(512,2) CAS_W(512,1)
        #undef CAS_W
        #undef CAS_L
    }

    // 5. gather candidate boxes (op-for-op identical reference box math),
    //    write candidate records into the ghist window this block consumed (16 KB).
    if (tid < KC){
        u32 bb = (u32)(v >> 32);
        u32 idx = 0xFFFFFFFFu - (u32)(v & 0xFFFFFFFFull);
        int srcrow = (bb != 0u) ? (int)idx : 0;
        const float* p = predb + (size_t)srcrow*6;
        const float2 p01 = *(const float2*)(p);
        const float2 p23 = *(const float2*)(p + 2);
        const float2 p45 = *(const float2*)(p + 4);
        float cx = p01.x, cy = p01.y, w = p23.x, h = p23.y, ob = p45.x, cf = p45.y;
        float x1 = cx - w * 0.5f, y1 = cy - h * 0.5f;
        float x2 = cx + w * 0.5f, y2 = cy + h * 0.5f;
        float4* cw = reinterpret_cast<float4*>(ghist) + ((size_t)b*KC + tid)*2;
        cw[0] = make_float4(x1, y1, x2, y2);
        cw[1] = make_float4(fmaxf(x2 - x1, 0.f) * fmaxf(y2 - y1, 0.f),
                            ob, cf, __uint_as_float(bb));
    }
}

// ---- K2b: IoU masks, 4 blocks/batch x 9 waves = 36 pairs, + copy slice 3 ----
//      off-diag (c<d): column mask masks[b][c*512 + d*64+lane] bit t =
//        (cand c*64+t suppresses cand d*64+lane)
//      diag (c==d): VICTIM mask vmask[b][c*64+lane] bit t =
//        (cand c*64+lane suppresses cand c*64+t), i.e. t>lane — same IoU values.
__global__ __launch_bounds__(576) void k2b_iou(const float4* __restrict__ cand,
        u64* __restrict__ masks, u64* __restrict__ vmasks,
        const float4* __restrict__ feat4, float* __restrict__ out, int copyB)
{
    __shared__ float4 s_box[KC];
    __shared__ float s_area[KC];
    const int tid = threadIdx.x;

    if ((int)blockIdx.x >= BATCH*4){              // copy role: [CSL2, CSL3)
        const int nthr = copyB * 576;
        float4* dst = reinterpret_cast<float4*>(out + FEAT_OFF);
        for (int i = CSL2 + ((int)blockIdx.x - BATCH*4)*576 + tid; i < CSL3; i += nthr)
            dst[i] = feat4[i];
        return;
    }

    const int b = (int)blockIdx.x >> 2, q = (int)blockIdx.x & 3;
    const float4* cb = cand + (size_t)b*KC*2;

    for (int i = tid; i < KC; i += 576){
        s_box[i] = cb[2*i];
        s_area[i] = cb[2*i+1].x;
    }
    __syncthreads();

    const int wv = tid >> 6, lane = tid & 63;
    const int p = q*9 + wv;                       // [0,36): every wave owns one pair
    int d = 0; while ((d+1)*(d+2)/2 <= p) d++;
    const int c = p - d*(d+1)/2;
    const int j = d*64 + lane;
    const float4 bj = s_box[j];
    const float aj = s_area[j];
    const bool isdiag = (c == d);
    u64 acc = 0ull;
    for (int t = 0; t < 64; t++){
        const float4 bi = s_box[c*64 + t];        // wave-uniform -> broadcast
        const float ai = s_area[c*64 + t];
        float lx = fmaxf(bi.x, bj.x), ly = fmaxf(bi.y, bj.y);
        float rx = fminf(bi.z, bj.z), ry = fminf(bi.w, bj.w);
        float iw = fmaxf(rx - lx, 0.f), ih = fmaxf(ry - ly, 0.f);
        float inter = iw * ih;
        float denom = ai + aj - inter + 1e-9f;
        const bool iouc = (inter > IOU_T * denom);
        // off-diag: suppressor side (all t). diag: victim side (t > lane).
        bool setb = isdiag ? (iouc && t > lane) : iouc;
        acc |= setb ? (1ull << t) : 0ull;
    }
    if (isdiag) vmasks[(size_t)b*KC + c*64 + lane] = acc;
    else        masks[(size_t)b*4096 + (size_t)c*512 + j] = acc;
}

// ---- K2c: bitset-greedy staged NMS (exact order) + outputs, + copy slice 4 ----
__global__ __launch_bounds__(512) void k2c_nms(const float4* __restrict__ cand,
        const u64* __restrict__ masks, const u64* __restrict__ vmasks,
        float* __restrict__ out,
        const float4* __restrict__ feat4, int copyB)
{
    __shared__ u64 s_masks[8];
    __shared__ u32 s_wpcnt[8], s_wpfx[8];
    __shared__ int s_outidx[MAXDET];
    __shared__ int s_outcnt;

    const int tid = threadIdx.x;

    if ((int)blockIdx.x >= BATCH){                // copy role: [CSL3, FEAT4_N)
        const int nthr = copyB * 512;
        float4* dst = reinterpret_cast<float4*>(out + FEAT_OFF);
        for (int i = CSL3 + ((int)blockIdx.x - BATCH)*512 + tid; i < FEAT4_N; i += nthr)
            dst[i] = feat4[i];
        return;
    }

    const int b = blockIdx.x;
    const int wave = tid >> 6, lane = tid & 63;
    const float4* cb = cand + (size_t)b*KC*2;
    const u64* mb = masks + (size_t)b*4096;

    const float4 meta = cb[2*tid + 1];            // (area, obj, conf, scorebits)
    const bool alive0 = (__float_as_uint(meta.w) != 0u);
    const u64 vm = vmasks[(size_t)b*KC + tid];    // my victim mask (within my block)
    u64 pre[7];
    #pragma unroll
    for (int e = 0; e < 7; e++) pre[e] = (e < wave) ? mb[(size_t)e*512 + tid] : 0ull;

    for (int c = 0; c < 8; c++){
        if (wave == c){
            bool alive = alive0;
            #pragma unroll
            for (int e = 0; e < 7; e++)
                if (e < c) alive = alive && ((pre[e] & s_masks[e]) == 0ull);
            // bitset greedy: A bit t = alive; survivors clear their victims (t'>t).
            u64 A = __ballot(alive);
            #pragma unroll
            for (int t = 0; t < 64; t++){
                const u64 m = shflidx_u64(vm, t);     // victim mask of cand c*64+t
                if ((A >> t) & 1ull) A &= ~m;         // wave-uniform
            }
            if (lane == 0) s_masks[c] = A;
        }
        __syncthreads();
    }

    if (tid < 8) s_wpcnt[tid] = (u32)__popcll(s_masks[tid]);
    __syncthreads();
    if (tid == 0){
        u32 run = 0;
        #pragma unroll
        for (int w = 0; w < 8; w++){ s_wpfx[w] = run; run += s_wpcnt[w]; }
        s_outcnt = (int)(run < MAXDET ? run : MAXDET);
    }
    __syncthreads();
    {
        const u64 wd = s_masks[wave];
        if ((wd >> lane) & 1ull){
            u32 rank = s_wpfx[wave] + (u32)__popcll(wd & ((1ull << lane) - 1ull));
            if (rank < MAXDET) s_outidx[rank] = tid;
        }
    }
    __syncthreads();
    if (tid < MAXDET){
        const int obase = (b * MAXDET + tid) * 7;
        if (tid < s_outcnt){
            int c = s_outidx[tid];
            float4 bx = cb[2*c];
            float4 mt = cb[2*c + 1];
            out[obase+0] = bx.x; out[obase+1] = bx.y;
            out[obase+2] = bx.z; out[obase+3] = bx.w;
            out[obase+4] = mt.y; out[obase+5] = mt.z;
            out[obase+6] = 0.f;                     // class_pred == 0 (NUM_CLASSES==1)
            out[MASK_OFF + b*MAXDET + tid] = 1.f;
        } else {
            #pragma unroll
            for (int q = 0; q < 7; q++) out[obase+q] = 0.f;
            out[MASK_OFF + b*MAXDET + tid] = 0.f;
        }
    }
}

extern "C" void kernel_launch(void* const* d_in, const int* in_sizes, int n_in,
                              void* d_out, int out_size, void* d_ws, size_t ws_size,
                              hipStream_t stream) {
    (void)in_sizes; (void)n_in; (void)out_size;
    const float* pred = (const float*)d_in[0];
    const float* feat = (const float*)d_in[1];
    float* out = (float*)d_out;

    const size_t hkeyBytes = (size_t)BATCH * NBLK1 * HBUF * 8;   // 1,310,720
    const size_t cntBytes  = (size_t)BATCH * NBLK1 * 4;          // 4,096
    const size_t histBytes = (size_t)BATCH * NBLK1 * NBINS * 4;  // 262,144
    const size_t maxBytes  = (size_t)BATCH * NBLK1 * 4;          // 4,096
    const size_t needBytes = hkeyBytes + cntBytes + histBytes + maxBytes; // unchanged

    char* base; bool fused;
    if (ws_size >= needBytes){ base = (char*)d_ws; fused = true; }
    else { base = (char*)(out + FEAT_OFF); fused = false; }   // not-yet-written features

    u64* hkeyp  = (u64*)base;
    u32* blkcnt = (u32*)(base + hkeyBytes);
    u32* ghist  = (u32*)(base + hkeyBytes + cntBytes);
    float* blkmax = (float*)(base + hkeyBytes + cntBytes + histBytes);
    // aliases (no extra workspace): cand[b] overwrites exactly the ghist window
    // block b consumed in k2a; masks+vmasks overwrite hkey after k2a consumed it.
    float4* cand = (float4*)ghist;                // 16 * 16384 B == histBytes exactly
    u64* masks   = hkeyp;                         // 16 * 32768 B = 512 KB
    u64* vmasks  = hkeyp + (size_t)BATCH*4096;    // +16 * 4096 B = 64 KB (<=1.31MB)

    if (fused){
        k1_score<<<dim3(K1CPB + BATCH*NBLK1), dim3(512), 0, stream>>>(
            pred, hkeyp, blkcnt, ghist, blkmax, (const float4*)feat, out, K1CPB);
        k2a_sel<<<dim3(BATCH + K2ACPB), dim3(1024), 0, stream>>>(
            pred, hkeyp, blkcnt, ghist, blkmax, (const float4*)feat, out, K2ACPB);
        k2b_iou<<<dim3(BATCH*4 + K2BCPB), dim3(576), 0, stream>>>(
            cand, masks, vmasks, (const float4*)feat, out, K2BCPB);
        k2c_nms<<<dim3(BATCH + K2CCPB), dim3(512), 0, stream>>>(
            cand, masks, vmasks, out, (const float4*)feat, K2CCPB);
    } else {
        // scratch lives in the feature output region -> copy must run LAST
        k1_score<<<dim3(BATCH*NBLK1), dim3(512), 0, stream>>>(
            pred, hkeyp, blkcnt, ghist, blkmax, (const float4*)feat, out, 0);
        k2a_sel<<<dim3(BATCH), dim3(1024), 0, stream>>>(
            pred, hkeyp, blkcnt, ghist, blkmax, (const float4*)feat, out, 0);
        k2b_iou<<<dim3(BATCH*4), dim3(576), 0, stream>>>(
            cand, masks, vmasks, (const float4*)feat, out, 0);
        k2c_nms<<<dim3(BATCH), dim3(512), 0, stream>>>(
            cand, masks, vmasks, out, (const float4*)feat, 0);
        copy_kernel<<<dim3(1024), dim3(256), 0, stream>>>(
            (const float4*)feat, (float4*)(out + FEAT_OFF));
    }
}

// Round 4
// 133.657 us; speedup vs baseline: 1.1717x; 1.0127x over previous
//
#include <hip/hip_runtime.h>
#include <stdint.h>

typedef unsigned int u32;
typedef unsigned long long u64;

#define BATCH 16
#define NBOX  48384
#define KC    512
#define MAXDET 100
#define CONF_T 0.25f
#define HCUT   0.75f     // high cut: top-512 boundary ~0.857 (product of uniforms)
#define IOU_T  0.45f
#define DET_FLOATS (BATCH*MAXDET*7)            // 11200
#define MASK_OFF   DET_FLOATS                  // 11200
#define FEAT_OFF   (DET_FLOATS + BATCH*MAXDET) // 12800
#define FEAT_N     (BATCH*256*48*48)           // 9437184
#define FEAT4_N    (FEAT_N/4)                  // 2359296

#define CAPH  4096       // per-batch staged-list cap (mean 1656, sd ~40)
#define HBUF  160        // per-block high buffer (mean 26, sd ~5 -> 26 sigma)
#define NBINS 64         // score-histogram bins over [0.75, 1.0)
#define NBLK1 64         // K1 score blocks per batch
#define BOXPB 756        // NBOX / NBLK1

// feature-copy slices, one per launch (overlap copy with latency-bound phases)
#define F64   (FEAT4_N/64)       // 36864
#define CSL1  (13*F64)           // k1 slice: [0, CSL1)
#define CSL2  (50*F64)           // k2a slice: [CSL1, CSL2)   (37/64)
#define CSL3  (56*F64)           // k2b slice: [CSL2, CSL3)   (6/64)
                                 // k2c slice: [CSL3, FEAT4_N) (8/64)
#define K1CPB  256
#define K2ACPB 480
#define K2BCPB 384
#define K2CCPB 240

__device__ __forceinline__ u64 xorred_u64(u64 v, int m){
    u32 lo = __shfl_xor((u32)(v & 0xFFFFFFFFull), m, 64);
    u32 hi = __shfl_xor((u32)(v >> 32), m, 64);
    return ((u64)hi << 32) | lo;
}
__device__ __forceinline__ u64 shflxor_u64(u64 v, int j){
    u32 lo = __shfl_xor((u32)(v & 0xFFFFFFFFull), j, 64);
    u32 hi = __shfl_xor((u32)(v >> 32), j, 64);
    return ((u64)hi << 32) | lo;
}
__device__ __forceinline__ u64 shflidx_u64(u64 v, int src){
    u32 lo = (u32)__shfl((int)(u32)(v & 0xFFFFFFFFull), src, 64);
    u32 hi = (u32)__shfl((int)(u32)(v >> 32), src, 64);
    return ((u64)hi << 32) | lo;
}
__device__ __forceinline__ int score_bin(float sc){
    int bin = (int)((sc - 0.75f) * 256.0f);     // monotone float->bin (identical in k1/k2a)
    return bin > 63 ? 63 : bin;
}

// ---- K1: copy blocks (slice 1) + scoring blocks (direct float2 reads) ----
__global__ __launch_bounds__(512) void k1_score(const float* __restrict__ pred,
        u64* __restrict__ hkey, u32* __restrict__ blkcnt, u32* __restrict__ ghist,
        float* __restrict__ blkmax, const float4* __restrict__ feat4,
        float* __restrict__ out, int copyB)
{
    __shared__ u64 s_hb[HBUF];
    __shared__ u32 s_hist[NBINS];
    __shared__ u32 s_hc;
    __shared__ float s_wm[8];

    const int tid = threadIdx.x;

    if ((int)blockIdx.x < copyB){                 // feature-copy role: [0, CSL1)
        const int nthr = copyB * 512;
        float4* dst = reinterpret_cast<float4*>(out + FEAT_OFF);
        for (int i = (int)blockIdx.x*512 + tid; i < CSL1; i += nthr)
            dst[i] = feat4[i];
        return;
    }

    const int sid = (int)blockIdx.x - copyB;      // score-block id in [0, 1024)
    const int b = sid >> 6, blk = sid & 63;
    if (tid == 0) s_hc = 0u;
    if (tid < NBINS) s_hist[tid] = 0u;
    __syncthreads();

    const float* pb = pred + ((size_t)b*NBOX + (size_t)blk*BOXPB)*6;
    float m = 0.f;
    for (int i = tid; i < BOXPB; i += 512){
        const float2 oc = *(const float2*)(pb + (size_t)i*6 + 4);  // 8B-aligned
        const float sc = oc.x * oc.y;                    // obj * class_conf
        m = fmaxf(m, sc);
        if (sc >= HCUT){
            const u32 slot = atomicAdd(&s_hc, 1u);       // LDS atomic only (~26/block)
            const u32 idx = (u32)(blk*BOXPB + i);
            if (slot < (u32)HBUF)
                s_hb[slot] = ((u64)__float_as_uint(sc) << 32) | (u64)(0xFFFFFFFFu - idx);
            atomicAdd(&s_hist[score_bin(sc)], 1u);
        }
    }
    #pragma unroll
    for (int off = 32; off >= 1; off >>= 1) m = fmaxf(m, __shfl_xor(m, off, 64));
    if ((tid & 63) == 0) s_wm[tid >> 6] = m;
    __syncthreads();                 // all scoring done; s_hc/s_hist/s_hb final
    if (tid == 0){
        float mm = s_wm[0];
        #pragma unroll
        for (int w = 1; w < 8; w++) mm = fmaxf(mm, s_wm[w]);
        blkmax[sid] = mm;
        blkcnt[sid] = s_hc;          // RAW count; > HBUF forces k2a slow path
    }
    if (tid < NBINS) ghist[(size_t)sid*NBINS + tid] = s_hist[tid];
    const u32 hn = (s_hc < (u32)HBUF ? s_hc : (u32)HBUF);
    for (u32 i = tid; i < hn; i += 512)
        hkey[(size_t)sid*HBUF + i] = s_hb[i];
}

// ---- standalone feature copy (fallback path only; runs LAST to free scratch) ----
__global__ void copy_kernel(const float4* __restrict__ src, float4* __restrict__ dst){
    int stride = gridDim.x * blockDim.x;
    for (int i = blockIdx.x*blockDim.x + threadIdx.x; i < FEAT4_N; i += stride)
        dst[i] = src[i];
}

// ---- K2a: per-batch select + sort + gather (16 compute blocks x 512 + copy slice 2) ----
//      block=512 (8 waves): sort uses all waves; fewer barriers/LDS contention vs 1024.
//      cand[b][i] = { float4 box ; float4 (area, obj, conf, scorebits) }  (32 B)
__global__ __launch_bounds__(512) void k2a_sel(
        const float* __restrict__ pred, const u64* __restrict__ hkey,
        const u32* __restrict__ blkcnt, u32* ghist /*aliased with cand output*/,
        const float* __restrict__ blkmax,
        const float4* __restrict__ feat4, float* __restrict__ out, int copyB)
{
    __shared__ u64 s_list[CAPH];     // 32 KB staged high list
    __shared__ u64 s_key[KC];        // 4 KB (low 32 aliased as slow-pass-A scratch)
    __shared__ u32 s_scr[1024];      // 4 KB: hist partials (fast) / hist4 (slow)
    __shared__ u64 s_tie[256];       // 2 KB: pivot-bin tie keys (fast)
    __shared__ u32 s_eqidx[256];     // 1 KB: exact-pivot tie indices (slow)
    __shared__ u32 s_pfx[64], s_cnt[64];
    __shared__ float s_thresh;
    __shared__ u32 s_Mh, s_maxc, s_pivbin, s_need, s_fastok;
    __shared__ u32 s_prefix, s_k, s_cntgt, s_cnteq;
    __shared__ int s_vM;

    const int tid = threadIdx.x;

    if ((int)blockIdx.x >= BATCH){                // copy role: [CSL1, CSL2)
        const int nthr = copyB * 512;
        float4* dst = reinterpret_cast<float4*>(out + FEAT_OFF);
        for (int i = CSL1 + ((int)blockIdx.x - BATCH)*512 + tid; i < CSL2; i += nthr)
            dst[i] = feat4[i];
        return;
    }

    const int b = blockIdx.x;
    const float* predb = pred + (size_t)b*NBOX*6;

    // 1. wave0: batch max -> threshold; wave1: counts, prefix, total, max
    {
        if (tid < 64){
            float vv = blkmax[b*NBLK1 + tid];
            #pragma unroll
            for (int off = 32; off >= 1; off >>= 1) vv = fmaxf(vv, __shfl_xor(vv, off, 64));
            if (tid == 0){
                float t = CONF_T; int g = 0;
                while (vv < t && g < 256){ t = fmaxf(t - 0.1f, t * 0.1f); g++; }
                s_thresh = t;
                s_cntgt = 0u; s_cnteq = 0u; s_fastok = 0u;
            }
        } else if (tid < 128){
            const int l = tid - 64;
            u32 c = blkcnt[b*NBLK1 + l];
            s_cnt[l] = c;
            u32 p = c;
            #pragma unroll
            for (int off = 1; off < 64; off <<= 1){
                u32 o = __shfl_up(p, off, 64);
                if (l >= off) p += o;
            }
            s_pfx[l] = p - c;                     // exclusive prefix
            u32 mc = c;
            #pragma unroll
            for (int off = 32; off >= 1; off >>= 1) mc = (u32)max(mc, __shfl_xor(mc, off, 64));
            if (l == 63) s_Mh = p;                // inclusive total at last lane
            if (l == 0)  s_maxc = mc;
        }
    }
    __syncthreads();
    const u32 Mh = s_Mh;
    const bool fastm = (Mh >= (u32)KC) && (Mh <= (u32)CAPH) && (s_maxc <= (u32)HBUF);

    // 2. fast: stage fixed-slot segments into contiguous LDS + combine histograms
    if (fastm){
        const int wv = tid >> 6, ln = tid & 63;   // 8 waves: 8 segments each
        #pragma unroll
        for (int q = 0; q < 8; q++){
            const int s = wv + q*8;
            const u32 n = s_cnt[s], base = s_pfx[s];
            const u64* src = hkey + (size_t)(b*NBLK1 + s)*HBUF;
            for (u32 i = ln; i < n; i += 64) s_list[base + i] = src[i];
        }
        const int j = tid & 63, g = tid >> 6;     // 8 groups x 8 rows
        const u32* gh = ghist + (size_t)b*NBLK1*NBINS;
        u32 acc = 0;
        #pragma unroll
        for (int r = 0; r < 8; r++) acc += gh[(g + r*8)*64 + j];
        s_scr[g*64 + j] = acc;
    }
    __syncthreads();
    if (fastm && tid < 64){                      // wave 0: pivot-bin pick
        u32 h = 0;
        #pragma unroll
        for (int g = 0; g < 8; g++) h += s_scr[g*64 + tid];
        u32 c = h;                               // inclusive suffix over bins (high=large)
        #pragma unroll
        for (int off = 1; off < 64; off <<= 1){
            u32 o = __shfl_down(c, off, 64);
            c += (tid + off < 64) ? o : 0u;
        }
        const u32 above = c - h;                 // count in bins > tid
        if (above < (u32)KC && above + h >= (u32)KC){   // unique crossing bin
            s_pivbin = (u32)tid;
            s_need = (u32)KC - above;
            s_fastok = (h <= 256u) ? 1u : 0u;    // tie buffer capacity gate
        }
    }
    __syncthreads();
    const bool fsel = fastm && (s_fastok != 0u);

    if (fsel){
        // 3a. partition of staged list, wave-aggregated LDS atomics (validated r2)
        const u32 pb = s_pivbin;
        const u32 lane = (u32)(tid & 63);
        const u64 below = (1ull << lane) - 1ull;
        for (u32 i0 = 0; i0 < Mh; i0 += 512){
            const u32 i = i0 + (u32)tid;
            const bool inr = (i < Mh);
            const u64 key = inr ? s_list[i] : 0ull;
            u32 j2 = 0u;
            if (inr){
                const float sc = __uint_as_float((u32)(key >> 32));
                j2 = (u32)score_bin(sc);
            }
            const bool isgt = inr && (j2 > pb);
            const bool iseq = inr && (j2 == pb);
            const u64 mg = __ballot(isgt);
            const u64 me = __ballot(iseq);
            u32 bg = 0u, be = 0u;
            if (lane == 0u){
                bg = atomicAdd(&s_cntgt, (u32)__popcll(mg));
                be = atomicAdd(&s_cnteq, (u32)__popcll(me));
            }
            bg = (u32)__shfl((int)bg, 0, 64);
            be = (u32)__shfl((int)be, 0, 64);
            if (isgt){
                const u32 sl = bg + (u32)__popcll(mg & below);
                if (sl < (u32)KC) s_key[sl] = key;
            } else if (iseq){
                const u32 e = be + (u32)__popcll(me & below);
                if (e < 256u) s_tie[e] = key;
            }
        }
        __syncthreads();
        // parallel tie rank: keys unique -> rank by value, slot g0+r. Exact.
        {
            const u32 g0v = (s_cntgt < (u32)KC) ? s_cntgt : (u32)KC;
            u32 ecv = (s_cnteq < 256u) ? s_cnteq : 256u;
            u32 needv = (s_need < ecv) ? s_need : ecv;
            if (tid < (int)ecv){
                const u64 me2 = s_tie[tid];
                u32 r = 0;
                for (u32 u2 = 0; u2 < ecv; ++u2) r += (s_tie[u2] > me2) ? 1u : 0u;
                if (r < needv && g0v + r < (u32)KC) s_key[g0v + r] = me2;
            }
            for (int i = (int)(g0v + needv) + tid; i < KC; i += 512) s_key[i] = 0ull;
        }
        __syncthreads();
    } else {
        // 3b. slow path (never taken with this data): full radix recomputing from pred
        const float thresh = s_thresh;
        const u32 base8 = __float_as_uint(thresh) >> 24;
        u32 (*s_hist4)[256] = reinterpret_cast<u32(*)[256]>(s_scr);
        {   // pass A: 16-bin packed-register histogram (thresh > max/10 -> <16 bins)
            u64 c0=0, c1=0, c2=0, c3=0;
            for (int i = tid; i < NBOX; i += 512){
                const float* pp = predb + (size_t)i*6;
                float sc = pp[4] * pp[5];
                if (sc >= thresh){
                    u32 d = (__float_as_uint(sc) >> 24) - base8; if (d > 15u) d = 15u;
                    u64 inc = 1ull << (16*(d & 3u)); u32 q = d >> 2;
                    c0 += (q==0u)?inc:0ull; c1 += (q==1u)?inc:0ull;
                    c2 += (q==2u)?inc:0ull; c3 += (q==3u)?inc:0ull;
                }
            }
            #pragma unroll
            for (int off = 32; off >= 1; off >>= 1){
                c0 += xorred_u64(c0,off); c1 += xorred_u64(c1,off);
                c2 += xorred_u64(c2,off); c3 += xorred_u64(c3,off);
            }
            u64* warr = s_key;                   // scratch: 8 waves x 4 u64
            if ((tid & 63) == 0){
                int w = tid >> 6;
                warr[w*4+0]=c0; warr[w*4+1]=c1; warr[w*4+2]=c2; warr[w*4+3]=c3;
            }
            __syncthreads();
            if (tid < 16){
                u32 tot = 0;
                #pragma unroll
                for (int w = 0; w < 8; w++){
                    u64 vv = warr[w*4 + (tid >> 2)];
                    tot += (u32)((vv >> (16*(tid & 3))) & 0xFFFFull);
                }
                s_hist4[0][tid] = tot;
            }
            __syncthreads();
            if (tid == 0){
                u32 h[16]; u32 tot = 0;
                #pragma unroll
                for (int d = 0; d < 16; d++){ h[d] = s_hist4[0][d]; tot += h[d]; }
                s_vM = (int)tot;
                s_k = KC; s_prefix = 0u;
                if (tot > (u32)KC){
                    u32 k = KC, c = 0; int d = 15;
                    for (; d >= 0; --d){ if (c + h[d] >= k) break; c += h[d]; }
                    if (d < 0) d = 0;
                    s_prefix = (base8 + (u32)d) << 24; s_k = k - c;
                }
            }
            __syncthreads();
        }
        const int vM = s_vM;
        if (vM > KC){
            for (int shift = 16; shift >= 0; shift -= 8){
                for (int z = tid; z < 1024; z += 512) ((u32*)s_hist4)[z] = 0u;
                __syncthreads();
                const u32 prefix = s_prefix;
                const u32 pmask = 0xFFFFFFFFu << (shift + 8);
                const int cpy = tid >> 8;        // 2 copies used of 4
                for (int i = tid; i < NBOX; i += 512){
                    const float* pp = predb + (size_t)i*6;
                    float sc = pp[4] * pp[5];
                    if (sc >= thresh){
                        u32 bb = __float_as_uint(sc);
                        if ((bb & pmask) == (prefix & pmask))
                            atomicAdd(&s_hist4[cpy][(bb >> shift) & 0xFFu], 1u);
                    }
                }
                __syncthreads();
                if (tid < 256)
                    s_hist4[0][tid] = s_hist4[0][tid] + s_hist4[1][tid]
                                    + s_hist4[2][tid] + s_hist4[3][tid];
                __syncthreads();
                if (tid < 64){                   // wave-parallel digit pick
                    const int l = tid;
                    u32 h0 = s_hist4[0][4*l+0], h1 = s_hist4[0][4*l+1];
                    u32 h2 = s_hist4[0][4*l+2], h3 = s_hist4[0][4*l+3];
                    u32 mysum = h0+h1+h2+h3;
                    u32 c = mysum;
                    #pragma unroll
                    for (int off = 1; off < 64; off <<= 1){
                        u32 o = __shfl_down(c, off, 64);
                        c += (l + off < 64) ? o : 0u;
                    }
                    u32 a3 = c - mysum;
                    u32 a2 = a3 + h3, a1 = a2 + h2, a0 = a1 + h1;
                    u32 k = s_k;
                    int sel = -1; u32 cab = 0;
                    if (a0 < k && a0 + h0 >= k){ sel = 0; cab = a0; }
                    if (a1 < k && a1 + h1 >= k){ sel = 1; cab = a1; }
                    if (a2 < k && a2 + h2 >= k){ sel = 2; cab = a2; }
                    if (a3 < k && a3 + h3 >= k){ sel = 3; cab = a3; }
                    if (sel >= 0){
                        s_prefix = prefix | ((u32)(4*l + sel) << shift);
                        s_k = k - cab;
                    }
                }
                __syncthreads();
            }
        }
        const u32 pivot = (vM > KC) ? s_prefix : 0u;
        const bool pivot0 = (vM <= KC);
        const int kneed = pivot0 ? 0 : (int)s_k;
        for (int i = tid; i < NBOX; i += 512){
            const float* pp = predb + (size_t)i*6;
            float sc = pp[4] * pp[5];
            if (sc < thresh) continue;
            u32 bb = __float_as_uint(sc);
            if (bb > pivot){
                u32 sl = atomicAdd(&s_cntgt, 1u);
                if (sl < (u32)KC) s_key[sl] = ((u64)bb << 32) | (u64)(0xFFFFFFFFu - (u32)i);
            } else if (!pivot0 && bb == pivot){
                u32 e = atomicAdd(&s_cnteq, 1u);
                if (e < 256u) s_eqidx[e] = (u32)i;
            }
        }
        __syncthreads();
        if (tid == 0){
            int g = (int)s_cntgt; if (g > KC) g = KC;
            int ec = (int)s_cnteq; if (ec > 256) ec = 256;
            int need = kneed < ec ? kneed : ec;
            for (int t = 0; t < need; t++){      // lowest indices first at exact pivot
                int mi = t;
                for (int u = t+1; u < ec; u++) if (s_eqidx[u] < s_eqidx[mi]) mi = u;
                u32 tmp = s_eqidx[mi]; s_eqidx[mi] = s_eqidx[t]; s_eqidx[t] = tmp;
                if (g < KC) s_key[g++] = ((u64)pivot << 32) | (u64)(0xFFFFFFFFu - tmp);
            }
            while (g < KC) s_key[g++] = 0ull;
        }
        __syncthreads();
    }

    // 4. bitonic sort 512 keys descending — shfl for j<=32, LDS for j in {64,128,256}
    u64 v = s_key[tid];
    {
        #define CAS_W(kk, j) \
            { \
                u64 p = shflxor_u64(v, (j)); \
                bool keepMax = (((tid & (kk)) == 0) == ((tid & (j)) == 0)); \
                u64 mx = (v > p) ? v : p, mn = (v > p) ? p : v; \
                v = keepMax ? mx : mn; \
            }
        #define CAS_L(kk, j) \
            __syncthreads(); \
            s_key[tid] = v; \
            __syncthreads(); \
            { \
                u64 p = s_key[tid ^ (j)]; \
                bool keepMax = (((tid & (kk)) == 0) == ((tid & (j)) == 0)); \
                u64 mx = (v > p) ? v : p, mn = (v > p) ? p : v; \
                v = keepMax ? mx : mn; \
            }
        CAS_W(2,1)
        CAS_W(4,2)  CAS_W(4,1)
        CAS_W(8,4)  CAS_W(8,2)  CAS_W(8,1)
        CAS_W(16,8) CAS_W(16,4) CAS_W(16,2) CAS_W(16,1)
        CAS_W(32,16) CAS_W(32,8) CAS_W(32,4) CAS_W(32,2) CAS_W(32,1)
        CAS_W(64,32) CAS_W(64,16) CAS_W(64,8) CAS_W(64,4) CAS_W(64,2) CAS_W(64,1)
        CAS_L(128,64)
        CAS_W(128,32) CAS_W(128,16) CAS_W(128,8) CAS_W(128,4) CAS_W(128,2) CAS_W(128,1)
        CAS_L(256,128) CAS_L(256,64)
        CAS_W(256,32) CAS_W(256,16) CAS_W(256,8) CAS_W(256,4) CAS_W(256,2) CAS_W(256,1)
        CAS_L(512,256) CAS_L(512,128) CAS_L(512,64)
        CAS_W(512,32) CAS_W(512,16) CAS_W(512,8) CAS_W(512,4) CAS_W(512,2) CAS_W(512,1)
        #undef CAS_W
        #undef CAS_L
    }

    // 5. gather candidate boxes (op-for-op identical reference box math),
    //    write candidate records into the ghist window this block consumed (16 KB).
    {
        u32 bb = (u32)(v >> 32);
        u32 idx = 0xFFFFFFFFu - (u32)(v & 0xFFFFFFFFull);
        int srcrow = (bb != 0u) ? (int)idx : 0;
        const float* p = predb + (size_t)srcrow*6;
        const float2 p01 = *(const float2*)(p);
        const float2 p23 = *(const float2*)(p + 2);
        const float2 p45 = *(const float2*)(p + 4);
        float cx = p01.x, cy = p01.y, w = p23.x, h = p23.y, ob = p45.x, cf = p45.y;
        float x1 = cx - w * 0.5f, y1 = cy - h * 0.5f;
        float x2 = cx + w * 0.5f, y2 = cy + h * 0.5f;
        float4* cw = reinterpret_cast<float4*>(ghist) + ((size_t)b*KC + tid)*2;
        cw[0] = make_float4(x1, y1, x2, y2);
        cw[1] = make_float4(fmaxf(x2 - x1, 0.f) * fmaxf(y2 - y1, 0.f),
                            ob, cf, __uint_as_float(bb));
    }
}

// ---- K2b: IoU masks, 9 blocks/batch x 4 waves = 36 pairs, + copy slice 3 ----
//      off-diag (c<d): column mask masks[b][c*512 + d*64+lane] bit t =
//        (cand c*64+t suppresses cand d*64+lane)
//      diag (c==d): VICTIM mask vmask[b][c*64+lane] bit t =
//        (cand c*64+lane suppresses cand c*64+t), i.e. t>lane — same IoU values.
__global__ __launch_bounds__(256) void k2b_iou(const float4* __restrict__ cand,
        u64* __restrict__ masks, u64* __restrict__ vmasks,
        const float4* __restrict__ feat4, float* __restrict__ out, int copyB)
{
    __shared__ float4 s_box[KC];
    __shared__ float s_area[KC];
    const int tid = threadIdx.x;

    if ((int)blockIdx.x >= BATCH*9){              // copy role: [CSL2, CSL3)
        const int nthr = copyB * 256;
        float4* dst = reinterpret_cast<float4*>(out + FEAT_OFF);
        for (int i = CSL2 + ((int)blockIdx.x - BATCH*9)*256 + tid; i < CSL3; i += nthr)
            dst[i] = feat4[i];
        return;
    }

    const int b = (int)blockIdx.x / 9, q = (int)blockIdx.x % 9;
    const float4* cb = cand + (size_t)b*KC*2;

    for (int i = tid; i < KC; i += 256){
        s_box[i] = cb[2*i];
        s_area[i] = cb[2*i+1].x;
    }
    __syncthreads();

    const int wv = tid >> 6, lane = tid & 63;
    const int p = q*4 + wv;                       // [0,36): every wave owns one pair
    int d = 0; while ((d+1)*(d+2)/2 <= p) d++;
    const int c = p - d*(d+1)/2;
    const int j = d*64 + lane;
    const float4 bj = s_box[j];
    const float aj = s_area[j];
    const bool isdiag = (c == d);
    u64 acc = 0ull;
    for (int t = 0; t < 64; t++){
        const float4 bi = s_box[c*64 + t];        // wave-uniform -> broadcast
        const float ai = s_area[c*64 + t];
        float lx = fmaxf(bi.x, bj.x), ly = fmaxf(bi.y, bj.y);
        float rx = fminf(bi.z, bj.z), ry = fminf(bi.w, bj.w);
        float iw = fmaxf(rx - lx, 0.f), ih = fmaxf(ry - ly, 0.f);
        float inter = iw * ih;
        float denom = ai + aj - inter + 1e-9f;
        const bool iouc = (inter > IOU_T * denom);
        // off-diag: suppressor side (all t). diag: victim side (t > lane).
        bool setb = isdiag ? (iouc && t > lane) : iouc;
        acc |= setb ? (1ull << t) : 0ull;
    }
    if (isdiag) vmasks[(size_t)b*KC + c*64 + lane] = acc;
    else        masks[(size_t)b*4096 + (size_t)c*512 + j] = acc;
}

// ---- K2c: bitset-greedy staged NMS (exact order) + outputs, + copy slice 4 ----
__global__ __launch_bounds__(512) void k2c_nms(const float4* __restrict__ cand,
        const u64* __restrict__ masks, const u64* __restrict__ vmasks,
        float* __restrict__ out,
        const float4* __restrict__ feat4, int copyB)
{
    __shared__ u64 s_masks[8];
    __shared__ u32 s_wpcnt[8], s_wpfx[8];
    __shared__ int s_outidx[MAXDET];
    __shared__ int s_outcnt;

    const int tid = threadIdx.x;

    if ((int)blockIdx.x >= BATCH){                // copy role: [CSL3, FEAT4_N)
        const int nthr = copyB * 512;
        float4* dst = reinterpret_cast<float4*>(out + FEAT_OFF);
        for (int i = CSL3 + ((int)blockIdx.x - BATCH)*512 + tid; i < FEAT4_N; i += nthr)
            dst[i] = feat4[i];
        return;
    }

    const int b = blockIdx.x;
    const int wave = tid >> 6, lane = tid & 63;
    const float4* cb = cand + (size_t)b*KC*2;
    const u64* mb = masks + (size_t)b*4096;

    const float4 meta = cb[2*tid + 1];            // (area, obj, conf, scorebits)
    const bool alive0 = (__float_as_uint(meta.w) != 0u);
    const u64 vm = vmasks[(size_t)b*KC + tid];    // my victim mask (within my block)
    u64 pre[7];
    #pragma unroll
    for (int e = 0; e < 7; e++) pre[e] = (e < wave) ? mb[(size_t)e*512 + tid] : 0ull;

    for (int c = 0; c < 8; c++){
        if (wave == c){
            bool alive = alive0;
            #pragma unroll
            for (int e = 0; e < 7; e++)
                if (e < c) alive = alive && ((pre[e] & s_masks[e]) == 0ull);
            // bitset greedy: A bit t = alive; survivors clear their victims (t'>t).
            u64 A = __ballot(alive);
            #pragma unroll
            for (int t = 0; t < 64; t++){
                const u64 m = shflidx_u64(vm, t);     // victim mask of cand c*64+t
                if ((A >> t) & 1ull) A &= ~m;         // wave-uniform
            }
            if (lane == 0) s_masks[c] = A;
        }
        __syncthreads();
    }

    if (tid < 8) s_wpcnt[tid] = (u32)__popcll(s_masks[tid]);
    __syncthreads();
    if (tid == 0){
        u32 run = 0;
        #pragma unroll
        for (int w = 0; w < 8; w++){ s_wpfx[w] = run; run += s_wpcnt[w]; }
        s_outcnt = (int)(run < MAXDET ? run : MAXDET);
    }
    __syncthreads();
    {
        const u64 wd = s_masks[wave];
        if ((wd >> lane) & 1ull){
            u32 rank = s_wpfx[wave] + (u32)__popcll(wd & ((1ull << lane) - 1ull));
            if (rank < MAXDET) s_outidx[rank] = tid;
        }
    }
    __syncthreads();
    if (tid < MAXDET){
        const int obase = (b * MAXDET + tid) * 7;
        if (tid < s_outcnt){
            int c = s_outidx[tid];
            float4 bx = cb[2*c];
            float4 mt = cb[2*c + 1];
            out[obase+0] = bx.x; out[obase+1] = bx.y;
            out[obase+2] = bx.z; out[obase+3] = bx.w;
            out[obase+4] = mt.y; out[obase+5] = mt.z;
            out[obase+6] = 0.f;                     // class_pred == 0 (NUM_CLASSES==1)
            out[MASK_OFF + b*MAXDET + tid] = 1.f;
        } else {
            #pragma unroll
            for (int q = 0; q < 7; q++) out[obase+q] = 0.f;
            out[MASK_OFF + b*MAXDET + tid] = 0.f;
        }
    }
}

extern "C" void kernel_launch(void* const* d_in, const int* in_sizes, int n_in,
                              void* d_out, int out_size, void* d_ws, size_t ws_size,
                              hipStream_t stream) {
    (void)in_sizes; (void)n_in; (void)out_size;
    const float* pred = (const float*)d_in[0];
    const float* feat = (const float*)d_in[1];
    float* out = (float*)d_out;

    const size_t hkeyBytes = (size_t)BATCH * NBLK1 * HBUF * 8;   // 1,310,720
    const size_t cntBytes  = (size_t)BATCH * NBLK1 * 4;          // 4,096
    const size_t histBytes = (size_t)BATCH * NBLK1 * NBINS * 4;  // 262,144
    const size_t maxBytes  = (size_t)BATCH * NBLK1 * 4;          // 4,096
    const size_t needBytes = hkeyBytes + cntBytes + histBytes + maxBytes; // unchanged

    char* base; bool fused;
    if (ws_size >= needBytes){ base = (char*)d_ws; fused = true; }
    else { base = (char*)(out + FEAT_OFF); fused = false; }   // not-yet-written features

    u64* hkeyp  = (u64*)base;
    u32* blkcnt = (u32*)(base + hkeyBytes);
    u32* ghist  = (u32*)(base + hkeyBytes + cntBytes);
    float* blkmax = (float*)(base + hkeyBytes + cntBytes + histBytes);
    // aliases (no extra workspace): cand[b] overwrites exactly the ghist window
    // block b consumed in k2a; masks+vmasks overwrite hkey after k2a consumed it.
    float4* cand = (float4*)ghist;                // 16 * 16384 B == histBytes exactly
    u64* masks   = hkeyp;                         // 16 * 32768 B = 512 KB
    u64* vmasks  = hkeyp + (size_t)BATCH*4096;    // +16 * 4096 B = 64 KB (<=1.31MB)

    if (fused){
        k1_score<<<dim3(K1CPB + BATCH*NBLK1), dim3(512), 0, stream>>>(
            pred, hkeyp, blkcnt, ghist, blkmax, (const float4*)feat, out, K1CPB);
        k2a_sel<<<dim3(BATCH + K2ACPB), dim3(512), 0, stream>>>(
            pred, hkeyp, blkcnt, ghist, blkmax, (const float4*)feat, out, K2ACPB);
        k2b_iou<<<dim3(BATCH*9 + K2BCPB), dim3(256), 0, stream>>>(
            cand, masks, vmasks, (const float4*)feat, out, K2BCPB);
        k2c_nms<<<dim3(BATCH + K2CCPB), dim3(512), 0, stream>>>(
            cand, masks, vmasks, out, (const float4*)feat, K2CCPB);
    } else {
        // scratch lives in the feature output region -> copy must run LAST
        k1_score<<<dim3(BATCH*NBLK1), dim3(512), 0, stream>>>(
            pred, hkeyp, blkcnt, ghist, blkmax, (const float4*)feat, out, 0);
        k2a_sel<<<dim3(BATCH), dim3(512), 0, stream>>>(
            pred, hkeyp, blkcnt, ghist, blkmax, (const float4*)feat, out, 0);
        k2b_iou<<<dim3(BATCH*9), dim3(256), 0, stream>>>(
            cand, masks, vmasks, (const float4*)feat, out, 0);
        k2c_nms<<<dim3(BATCH), dim3(512), 0, stream>>>(
            cand, masks, vmasks, out, (const float4*)feat, 0);
        copy_kernel<<<dim3(1024), dim3(256), 0, stream>>>(
            (const float4*)feat, (float4*)(out + FEAT_OFF));
    }
}